// Round 7
// baseline (311.716 us; speedup 1.0000x reference)
//
#include <hip/hip_runtime.h>
#include <hip/hip_bf16.h>
#include <cstdint>

#define N_NOTES 4096
#define SIZE 64
#define NE 14
#define NITER 5
#define MAXDEG 64
#define KTOT 960   /* 15*64 : 14 edge-type act chunks + h chunk */
#define HPAD 4113  /* h rows incl. zero pad rows 4096..4112 (dummy idx 0x1010=4112) */
#define PWN 184320 /* 3*4*30*512 fragment-packed Wt elements */
#define PUN 4096   /* 4*2*512 fragment-packed Ut elements */

typedef __attribute__((ext_vector_type(8))) short short8;
typedef __attribute__((ext_vector_type(4))) float float4v;

__device__ __forceinline__ ushort f2bf(float f){
  union{float f; uint32_t u;} x; x.f=f;
  uint32_t r = x.u + 0x7fffu + ((x.u>>16)&1u);
  return (ushort)(r>>16);
}
__device__ __forceinline__ float bf2f(ushort h){
  union{uint32_t u; float f;} x; x.u=((uint32_t)h)<<16; return x.f;
}
__device__ __forceinline__ void split_bf(float v, ushort& hi, ushort& lo){
  hi = f2bf(v);
  lo = f2bf(v - bf2f(hi));   // hi+lo ~ 16-17 mantissa bits
}

// ---- zero/init workspace
__global__ __launch_bounds__(256) void k_zero(int* __restrict__ deg, uint32_t* __restrict__ adj32,
                                              float* __restrict__ h0pad, float* __restrict__ h1pad){
  int i = blockIdx.x*256 + threadIdx.x;
  if (i < NE*N_NOTES) deg[i] = 0;
  for (int j = i; j < NE*N_NOTES*MAXDEG/2; j += gridDim.x*256)
    adj32[j] = 0x10101010u;                    // two ushorts of 4112 (dummy -> zero row)
  if (i < (HPAD-N_NOTES)*SIZE){ h0pad[i] = 0.f; h1pad[i] = 0.f; }
}

// ---- Pass 1: edge_matrix [14,4096,4096] f32 -> per-(e,n) adjacency (column lists)
__global__ __launch_bounds__(256) void k_build(const float4v* __restrict__ edge4,
                                               int* __restrict__ deg,
                                               ushort* __restrict__ adj){
  int row = blockIdx.x;            // e*4096 + m
  int e = row >> 12, m = row & 4095;
  const float4v* p = edge4 + (size_t)row * (N_NOTES/4);
  int t = threadIdx.x;
  #pragma unroll
  for (int i=0;i<4;i++){
    int idx4 = t + i*256;
    float4v v = p[idx4];
    int nbase = idx4*4;
    #pragma unroll
    for (int j=0;j<4;j++){
      if (v[j] != 0.0f){
        int n = nbase + j;
        int slot = atomicAdd(&deg[(e<<12)+n], 1);
        if (slot < MAXDEG) adj[(size_t)((e<<12)+n)*MAXDEG + slot] = (ushort)m;
      }
    }
  }
}

// ---- Pack weights into MFMA-fragment order (coalesced B loads)
__global__ __launch_bounds__(256) void k_pack(const float* __restrict__ wz, const float* __restrict__ wr,
                                              const float* __restrict__ wh, const float* __restrict__ uz,
                                              const float* __restrict__ ur, const float* __restrict__ uh,
                                              ushort* __restrict__ PWH, ushort* __restrict__ PWL,
                                              ushort* __restrict__ PUH, ushort* __restrict__ PUL){
  int idx = blockIdx.x*256 + threadIdx.x;
  if (idx < PWN){
    int j = idx & 7, lane = (idx>>3)&63, t = idx>>9;   // t = (g*4+cb)*30+kk
    int kk = t % 30, wg = t/30; int cb = wg & 3, g = wg >> 2;
    int col = g*64 + cb*16 + (lane&15);
    int k = kk*32 + ((lane>>4)<<3) + j;
    int e = k >> 6, d = k & 63, f = col & 63;
    float v;
    if (e < NE){
      const float* wp = (g==0)?wz:(g==1)?wr:wh;
      v = wp[(e*64 + d)*64 + f];
    } else {
      v = (g==0) ? uz[d*64+f] : (g==1) ? ur[d*64+f] : 0.0f;
    }
    ushort hi,lo; split_bf(v,hi,lo);
    PWH[idx]=hi; PWL[idx]=lo;
  } else if (idx < PWN + PUN){
    int i2 = idx - PWN;
    int j = i2 & 7, lane = (i2>>3)&63, t = i2>>9;      // t = cb*2+kk
    int kk = t & 1, cb = t >> 1;
    int col = cb*16 + (lane&15);
    int k = kk*32 + ((lane>>4)<<3) + j;
    float v = uh[k*64 + col];
    ushort hi,lo; split_bf(v,hi,lo);
    PUH[i2]=hi; PUL[i2]=lo;
  }
}

// ---- producer gather: one (e,row) unit per wave-quarter; fixed 16-slot unrolled
__device__ __forceinline__ void gather_store(const float4v* __restrict__ hin4,
                                             const ushort* __restrict__ adjRow,
                                             int mv, int dg, int qi, int ql,
                                             ushort* __restrict__ dH, ushort* __restrict__ dL){
  float4v a0={0.f,0.f,0.f,0.f}, a1=a0, a2=a0, a3=a0;
  #pragma unroll
  for (int k=0;k<16;k+=4){
    int m0 = __shfl(mv, qi*16 + k);
    int m1 = __shfl(mv, qi*16 + k+1);
    int m2 = __shfl(mv, qi*16 + k+2);
    int m3 = __shfl(mv, qi*16 + k+3);
    a0 += hin4[m0*16 + ql];
    a1 += hin4[m1*16 + ql];
    a2 += hin4[m2*16 + ql];
    a3 += hin4[m3*16 + ql];
  }
  if (dg > 16){                      // rare tail (~0.4% of units)
    for (int k=16;k<dg;k++){
      int m = adjRow[k];
      a0 += hin4[m*16 + ql];
    }
  }
  float4v acc = (a0 + a1) + (a2 + a3);
  ushort h0,h1,h2,h3,l0,l1,l2,l3;
  split_bf(acc[0],h0,l0); split_bf(acc[1],h1,l1);
  split_bf(acc[2],h2,l2); split_bf(acc[3],h3,l3);
  *(ushort4*)dH = make_ushort4(h0,h1,h2,h3);
  *(ushort4*)dL = make_ushort4(l0,l1,l2,l3);
}

// ---- Fused iteration: producer/consumer 15-stage pipeline over e-slots.
//      waves 12..15 gather e-slot s+1 into double-buffered LDS; waves 0..11 = (cb,g)
//      accumulate full-K MFMA per slot with B register-prefetched one stage ahead.
__global__ __launch_bounds__(1024, 4)
void k_fused(const int* __restrict__ deg, const ushort* __restrict__ adj,
             const ushort* __restrict__ PWH, const ushort* __restrict__ PWL,
             const ushort* __restrict__ PUH, const ushort* __restrict__ PUL,
             const float* __restrict__ bz, const float* __restrict__ br,
             const float* __restrict__ bh,
             const float* __restrict__ hin, float* __restrict__ hout,
             float* __restrict__ out, int last){
  __shared__ ushort AbH[2*16*72];    // [buf][row][72] hi
  __shared__ ushort AbL[2*16*72];    // lo
  __shared__ float  GSf[16*200];     // az|ar|ah final
  __shared__ ushort rhHs[16*72];
  __shared__ ushort rhLs[16*72];
  __shared__ float  zSf[1024];
  __shared__ float  rSf[1024];

  const int tid  = threadIdx.x;
  const int w    = tid >> 6;
  const int lane = tid & 63;
  const int l15  = lane & 15;
  const int koff = (lane >> 4) * 8;
  const int r0   = blockIdx.x * 16;
  const float4v* hin4 = (const float4v*)hin;

  const bool prod = (w >= 12);
  const int qi = lane >> 4, ql = lane & 15;
  const int cb = w & 3, g = w >> 2;  // consumer role (g<3 guaranteed for w<12)

  // ---------- producer prologue: slot 0 gather, slot-1 adjacency prefetch ----------
  int dg_c=0, mv_c=0, dg_n=0, mv_n=0, n=0, ri=0;
  if (prod){
    ri = (w-12)*4 + qi;
    n  = r0 + ri;
    int dg0 = deg[n];                                 // e=0
    int mv0 = adj[(size_t)n*MAXDEG + ql];
    int b1  = (1<<12) + n;
    dg_c = deg[b1];
    mv_c = adj[(size_t)b1*MAXDEG + ql];
    if (dg0 > MAXDEG) dg0 = MAXDEG;
    gather_store(hin4, adj + (size_t)n*MAXDEG, mv0, dg0, qi, ql,
                 &AbH[ri*72 + ql*4], &AbL[ri*72 + ql*4]);
  }

  // ---------- consumer prologue: B frags for kk=0,1 ----------
  short8 cH0,cL0,cH1,cL1,nH0,nL0,nH1,nL1;
  if (!prod){
    int t0 = ((g*4+cb)*30) << 9;
    cH0 = *(const short8*)(PWH + t0 + lane*8);
    cL0 = *(const short8*)(PWL + t0 + lane*8);
    cH1 = *(const short8*)(PWH + t0 + 512 + lane*8);
    cL1 = *(const short8*)(PWL + t0 + 512 + lane*8);
  }
  __syncthreads();

  // ---------- 15-stage pipeline ----------
  float4v acc = {0.f,0.f,0.f,0.f};
  #pragma unroll
  for (int s=0; s<15; ++s){
    if (prod){
      if (s < 12){                                    // adjacency prefetch for slot s+2 (<=13)
        int bn = ((s+2)<<12) + n;
        dg_n = deg[bn];
        mv_n = adj[(size_t)bn*MAXDEG + ql];
      }
      if (s < 13){                                    // gather slot s+1 into buf (s+1)&1
        int dgc = dg_c > MAXDEG ? MAXDEG : dg_c;
        int bb = ((s+1)&1)*1152 + ri*72 + ql*4;
        gather_store(hin4, adj + (size_t)(((s+1)<<12)+n)*MAXDEG, mv_c, dgc, qi, ql,
                     &AbH[bb], &AbL[bb]);
        dg_c = dg_n; mv_c = mv_n;
      } else if (s == 13){                            // slot 14 = h row copy -> buf 0
        float4v av = hin4[n*16 + ql];
        ushort h0,h1,h2,h3,l0,l1,l2,l3;
        split_bf(av[0],h0,l0); split_bf(av[1],h1,l1);
        split_bf(av[2],h2,l2); split_bf(av[3],h3,l3);
        int bb = ri*72 + ql*4;
        *(ushort4*)&AbH[bb] = make_ushort4(h0,h1,h2,h3);
        *(ushort4*)&AbL[bb] = make_ushort4(l0,l1,l2,l3);
      }
    } else {
      if (s < 14){                                    // B prefetch for stage s+1
        int tn = ((g*4+cb)*30 + 2*(s+1)) << 9;
        nH0 = *(const short8*)(PWH + tn + lane*8);
        nL0 = *(const short8*)(PWL + tn + lane*8);
        nH1 = *(const short8*)(PWH + tn + 512 + lane*8);
        nL1 = *(const short8*)(PWL + tn + 512 + lane*8);
      }
      const int ab = (s&1)*1152 + l15*72;
      short8 aH0 = *(const short8*)&AbH[ab + koff];
      short8 aL0 = *(const short8*)&AbL[ab + koff];
      short8 aH1 = *(const short8*)&AbH[ab + 32 + koff];
      short8 aL1 = *(const short8*)&AbL[ab + 32 + koff];
      acc = __builtin_amdgcn_mfma_f32_16x16x32_bf16(aH0,cH0,acc,0,0,0);
      acc = __builtin_amdgcn_mfma_f32_16x16x32_bf16(aH0,cL0,acc,0,0,0);
      acc = __builtin_amdgcn_mfma_f32_16x16x32_bf16(aL0,cH0,acc,0,0,0);
      acc = __builtin_amdgcn_mfma_f32_16x16x32_bf16(aH1,cH1,acc,0,0,0);
      acc = __builtin_amdgcn_mfma_f32_16x16x32_bf16(aH1,cL1,acc,0,0,0);
      acc = __builtin_amdgcn_mfma_f32_16x16x32_bf16(aL1,cH1,acc,0,0,0);
      if (s < 14){ cH0=nH0; cL0=nL0; cH1=nH1; cL1=nL1; }
    }
    __syncthreads();
  }

  // ---------- consumers publish final az/ar/ah ----------
  if (!prod){
    int crow0 = (lane>>4)*4;
    int colg = g*64 + cb*16 + l15;
    #pragma unroll
    for (int i=0;i<4;i++)
      GSf[(crow0+i)*200 + colg] = acc[i];
  }
  __syncthreads();

  // ---------- gates (all 1024 threads) ----------
  {
    int rr = tid >> 6, f = tid & 63;
    float az = GSf[rr*200 + f];
    float ar = GSf[rr*200 + 64 + f];
    float z  = 1.f/(1.f + expf(-(az + bz[f])));
    float rg = 1.f/(1.f + expf(-(ar + br[f])));
    float hv = hin[(size_t)(r0+rr)*64 + f];
    zSf[tid] = z; rSf[tid] = rg;
    ushort hi,lo; split_bf(rg*hv,hi,lo);
    rhHs[rr*72+f] = hi; rhLs[rr*72+f] = lo;
  }
  __syncthreads();

  // ---------- waves 0..3: T = rh @ Ut, blend, write ----------
  if (w < 4){
    const int colf = w*16 + l15;
    float4v acc2 = {0.f,0.f,0.f,0.f};
    #pragma unroll
    for (int kk=0; kk<2; ++kk){
      short8 aH = *(const short8*)&rhHs[l15*72 + kk*32 + koff];
      short8 aL = *(const short8*)&rhLs[l15*72 + kk*32 + koff];
      int boff = (((w<<1) + kk) << 9) + lane*8;
      short8 bH = *(const short8*)(PUH + boff);
      short8 bL = *(const short8*)(PUL + boff);
      acc2 = __builtin_amdgcn_mfma_f32_16x16x32_bf16(aH,bH,acc2,0,0,0);
      acc2 = __builtin_amdgcn_mfma_f32_16x16x32_bf16(aH,bL,acc2,0,0,0);
      acc2 = __builtin_amdgcn_mfma_f32_16x16x32_bf16(aL,bH,acc2,0,0,0);
    }
    const int crow0 = (lane>>4)*4;
    const float bhf = bh[colf];
    #pragma unroll
    for (int i=0;i<4;i++){
      int row = crow0 + i;
      float ah = GSf[row*200 + 128 + colf];
      float z  = zSf[row*64 + colf];
      float rg = rSf[row*64 + colf];
      float ht = tanhf(ah + acc2[i] + bhf);
      size_t idx = (size_t)(r0+row)*64 + colf;
      float hn = (1.f - z)*hin[idx] + rg*ht;
      hout[idx] = hn;
      if (last) out[idx] = hn;
    }
  }
}

extern "C" void kernel_launch(void* const* d_in, const int* in_sizes, int n_in,
                              void* d_out, int out_size, void* d_ws, size_t ws_size,
                              hipStream_t stream) {
  const float* x    = (const float*)d_in[0];
  const float* edge = (const float*)d_in[1];
  const float* wz   = (const float*)d_in[2];
  const float* wr   = (const float*)d_in[3];
  const float* wh   = (const float*)d_in[4];
  const float* uz   = (const float*)d_in[5];
  const float* ur   = (const float*)d_in[6];
  const float* uh   = (const float*)d_in[7];
  const float* bz   = (const float*)d_in[8];
  const float* br   = (const float*)d_in[9];
  const float* bh   = (const float*)d_in[10];
  float* out = (float*)d_out;

  char* ws = (char*)d_ws;
  size_t off = 0;
  auto alloc = [&](size_t bytes)->void*{
    void* p = ws + off;
    off = (off + bytes + 255) & ~(size_t)255;
    return p;
  };
  const size_t EN = (size_t)NE * N_NOTES;            // 57344
  const size_t ND = (size_t)N_NOTES * SIZE;          // 262144
  int*    deg  = (int*)   alloc(EN * 4);
  ushort* adj  = (ushort*)alloc(EN * MAXDEG * 2);
  ushort* PWH  = (ushort*)alloc((size_t)PWN * 2);
  ushort* PWL  = (ushort*)alloc((size_t)PWN * 2);
  ushort* PUH  = (ushort*)alloc((size_t)PUN * 2);
  ushort* PUL  = (ushort*)alloc((size_t)PUN * 2);
  float*  h0   = (float*) alloc((size_t)HPAD * SIZE * 4);
  float*  h1   = (float*) alloc((size_t)HPAD * SIZE * 4);

  k_zero <<<2048, 256, 0, stream>>>(deg, (uint32_t*)adj, h0 + ND, h1 + ND);
  k_build<<<NE*N_NOTES, 256, 0, stream>>>((const float4v*)edge, deg, adj);
  k_pack <<<(PWN + PUN)/256, 256, 0, stream>>>(wz, wr, wh, uz, ur, uh, PWH, PWL, PUH, PUL);
  hipMemcpyAsync(h0, x, ND*4, hipMemcpyDeviceToDevice, stream);

  float* hcur = h0;
  float* hnxt = h1;
  for (int it = 0; it < NITER; ++it){
    k_fused<<<N_NOTES/16, 1024, 0, stream>>>(deg, adj, PWH, PWL, PUH, PUL,
                                             bz, br, bh, hcur, hnxt,
                                             out, (it == NITER-1) ? 1 : 0);
    float* t = hcur; hcur = hnxt; hnxt = t;
  }
}

// Round 8
// 305.270 us; speedup vs baseline: 1.0211x; 1.0211x over previous
//
#include <hip/hip_runtime.h>
#include <hip/hip_bf16.h>
#include <cstdint>

#define N_NOTES 4096
#define SIZE 64
#define NE 14
#define NITER 5
#define MAXDEG 64
#define KTOT 960   /* 15*64 : 14 edge-type act chunks + h chunk */
#define ASTR 968   /* padded LDS k-stride (ushorts) */
#define HPAD 4113  /* h rows incl. zero pad rows 4096..4112 (dummy idx 0x1010=4112) */
#define PWN 184320 /* 3*4*30*512 fragment-packed Wt elements */
#define PUN 4096   /* 4*2*512 fragment-packed Ut elements */
#define PSTR 264   /* PS slot stride in f32 */

typedef __attribute__((ext_vector_type(8))) short short8;
typedef __attribute__((ext_vector_type(4))) float float4v;

__device__ __forceinline__ ushort f2bf(float f){
  union{float f; uint32_t u;} x; x.f=f;
  uint32_t r = x.u + 0x7fffu + ((x.u>>16)&1u);
  return (ushort)(r>>16);
}
__device__ __forceinline__ float bf2f(ushort h){
  union{uint32_t u; float f;} x; x.u=((uint32_t)h)<<16; return x.f;
}
__device__ __forceinline__ void split_bf(float v, ushort& hi, ushort& lo){
  hi = f2bf(v);
  lo = f2bf(v - bf2f(hi));   // hi+lo ~ 16-17 mantissa bits
}

// ---- zero/init workspace
__global__ __launch_bounds__(256) void k_zero(int* __restrict__ deg, uint32_t* __restrict__ adj32,
                                              float* __restrict__ h0pad, float* __restrict__ h1pad){
  int i = blockIdx.x*256 + threadIdx.x;
  if (i < NE*N_NOTES) deg[i] = 0;
  for (int j = i; j < NE*N_NOTES*MAXDEG/2; j += gridDim.x*256)
    adj32[j] = 0x10101010u;                    // two ushorts of 4112 (dummy -> zero row)
  if (i < (HPAD-N_NOTES)*SIZE){ h0pad[i] = 0.f; h1pad[i] = 0.f; }
}

// ---- Pass 1: edge_matrix [14,4096,4096] f32 -> per-(e,n) adjacency (column lists)
__global__ __launch_bounds__(256) void k_build(const float4v* __restrict__ edge4,
                                               int* __restrict__ deg,
                                               ushort* __restrict__ adj){
  int row = blockIdx.x;            // e*4096 + m
  int e = row >> 12, m = row & 4095;
  const float4v* p = edge4 + (size_t)row * (N_NOTES/4);
  int t = threadIdx.x;
  #pragma unroll
  for (int i=0;i<4;i++){
    int idx4 = t + i*256;
    float4v v = p[idx4];
    int nbase = idx4*4;
    #pragma unroll
    for (int j=0;j<4;j++){
      if (v[j] != 0.0f){
        int n = nbase + j;
        int slot = atomicAdd(&deg[(e<<12)+n], 1);
        if (slot < MAXDEG) adj[(size_t)((e<<12)+n)*MAXDEG + slot] = (ushort)m;
      }
    }
  }
}

// ---- Pack weights into MFMA-fragment order (coalesced B loads)
__global__ __launch_bounds__(256) void k_pack(const float* __restrict__ wz, const float* __restrict__ wr,
                                              const float* __restrict__ wh, const float* __restrict__ uz,
                                              const float* __restrict__ ur, const float* __restrict__ uh,
                                              ushort* __restrict__ PWH, ushort* __restrict__ PWL,
                                              ushort* __restrict__ PUH, ushort* __restrict__ PUL){
  int idx = blockIdx.x*256 + threadIdx.x;
  if (idx < PWN){
    int j = idx & 7, lane = (idx>>3)&63, t = idx>>9;   // t = (g*4+cb)*30+kk
    int kk = t % 30, wg = t/30; int cb = wg & 3, g = wg >> 2;
    int col = g*64 + cb*16 + (lane&15);
    int k = kk*32 + ((lane>>4)<<3) + j;
    int e = k >> 6, d = k & 63, f = col & 63;
    float v;
    if (e < NE){
      const float* wp = (g==0)?wz:(g==1)?wr:wh;
      v = wp[(e*64 + d)*64 + f];
    } else {
      v = (g==0) ? uz[d*64+f] : (g==1) ? ur[d*64+f] : 0.0f;
    }
    ushort hi,lo; split_bf(v,hi,lo);
    PWH[idx]=hi; PWL[idx]=lo;
  } else if (idx < PWN + PUN){
    int i2 = idx - PWN;
    int j = i2 & 7, lane = (i2>>3)&63, t = i2>>9;      // t = cb*2+kk
    int kk = t & 1, cb = t >> 1;
    int col = cb*16 + (lane&15);
    int k = kk*32 + ((lane>>4)<<3) + j;
    float v = uh[k*64 + col];
    ushort hi,lo; split_bf(v,hi,lo);
    PUH[i2]=hi; PUL[i2]=lo;
  }
}

// ---- one gather unit (e,n) handled by a wave-quarter; fixed-16 unrolled, f32 source
__device__ __forceinline__ void gather_unit(const float4v* __restrict__ hin4,
                                            const int* __restrict__ deg,
                                            const ushort* __restrict__ adj,
                                            int e, int n, int qi, int ql,
                                            ushort* __restrict__ dH, ushort* __restrict__ dL){
  float4v acc;
  if (e < NE){
    int base = (e<<12) + n;
    int dg = deg[base]; if (dg > MAXDEG) dg = MAXDEG;
    int mv = adj[(size_t)base*MAXDEG + ql];    // slots >= deg hold dummy 4112 -> zero row
    float4v a0={0.f,0.f,0.f,0.f}, a1=a0, a2=a0, a3=a0;
    #pragma unroll
    for (int k=0;k<16;k+=4){
      int m0 = __shfl(mv, qi*16 + k);
      int m1 = __shfl(mv, qi*16 + k+1);
      int m2 = __shfl(mv, qi*16 + k+2);
      int m3 = __shfl(mv, qi*16 + k+3);
      a0 += hin4[m0*16 + ql];
      a1 += hin4[m1*16 + ql];
      a2 += hin4[m2*16 + ql];
      a3 += hin4[m3*16 + ql];
    }
    if (dg > 16){                              // rare tail (~0.4% of units)
      const ushort* arow = adj + (size_t)base*MAXDEG;
      for (int k=16;k<dg;k++){
        int m = arow[k];
        a0 += hin4[m*16 + ql];
      }
    }
    acc = (a0 + a1) + (a2 + a3);
  } else {
    acc = hin4[n*16 + ql];                     // slot 14 = h itself
  }
  ushort h0,h1,h2,h3,l0,l1,l2,l3;
  split_bf(acc[0],h0,l0); split_bf(acc[1],h1,l1);
  split_bf(acc[2],h2,l2); split_bf(acc[3],h3,l3);
  *(ushort4*)dH = make_ushort4(h0,h1,h2,h3);
  *(ushort4*)dL = make_ushort4(l0,l1,l2,l3);
}

// ---- Fused iteration, rotating-wave pipeline:
//      gather pass p fills e-slots 4p..4p+3 == exactly the K-range of split-K group kq=p.
//      Step p: the 4 waves with kq==p-1 run their MFMA (data ready) while the other 12
//      waves gather pass p. Gather keeps 12-wave parallelism; PW stream overlaps gather.
__global__ __launch_bounds__(1024, 4)
void k_fused(const int* __restrict__ deg, const ushort* __restrict__ adj,
             const ushort* __restrict__ PWH, const ushort* __restrict__ PWL,
             const ushort* __restrict__ PUH, const ushort* __restrict__ PUL,
             const float* __restrict__ bz, const float* __restrict__ br,
             const float* __restrict__ bh,
             const float* __restrict__ hin, float* __restrict__ hout,
             float* __restrict__ out, int last){
  __shared__ ushort sh[31744];                 // 63488 B
  ushort* aHs = sh;                            // [16][ASTR]
  ushort* aLs = sh + 16*ASTR;
  float*  PSf = (float*)sh;                    // 48 slots * PSTR f32, aliased (used post-MFMA)
  ushort* rhH = sh + 25344;                    // byte 50688, 16*72
  ushort* rhL = sh + 26496;                    // byte 52992
  float*  zSf = (float*)(sh + 27648);          // byte 55296, 1024 f32
  float*  rSf = (float*)(sh + 29696);          // byte 59392, 1024 f32

  const int tid  = threadIdx.x;
  const int w    = tid >> 6;                   // wave 0..15
  const int lane = tid & 63;
  const int qi   = lane >> 4;
  const int ql   = lane & 15;
  const int l15  = lane & 15;
  const int koff = (lane >> 4) * 8;
  const int cb   = w & 3, kq = w >> 2;
  const int r0   = blockIdx.x * 16;
  const float4v* hin4 = (const float4v*)hin;

  // ---------- prologue: gather pass 0 (units 0..63, e=0..3), all 16 waves ----------
  {
    int u = w*4 + qi, e = u >> 4, ri = u & 15;
    gather_unit(hin4, deg, adj, e, r0+ri, qi, ql,
                &aHs[ri*ASTR + e*64 + ql*4], &aLs[ri*ASTR + e*64 + ql*4]);
  }
  __syncthreads();

  // ---------- 4-step rotating pipeline ----------
  float4v acc[3];
  #pragma unroll
  for (int g=0;g<3;g++) acc[g] = (float4v){0.f,0.f,0.f,0.f};

  #pragma unroll
  for (int p=1; p<=4; ++p){
    if (kq == p-1){
      // my K-range: kk in [ (p-1)*8, (p-1)*8+8 ), clamped to 30
      const int kk0 = (p-1)*8;
      #pragma unroll
      for (int kx=0; kx<8; ++kx){
        const int kk = kk0 + kx;
        if (kk < 30){
          short8 aH = *(const short8*)&aHs[l15*ASTR + kk*32 + koff];
          short8 aL = *(const short8*)&aLs[l15*ASTR + kk*32 + koff];
          #pragma unroll
          for (int g=0; g<3; ++g){
            int boff = (((g*4 + cb)*30 + kk) << 9) + lane*8;
            short8 bH = *(const short8*)(PWH + boff);
            short8 bL = *(const short8*)(PWL + boff);
            acc[g] = __builtin_amdgcn_mfma_f32_16x16x32_bf16(aH,bH,acc[g],0,0,0);
            acc[g] = __builtin_amdgcn_mfma_f32_16x16x32_bf16(aH,bL,acc[g],0,0,0);
            acc[g] = __builtin_amdgcn_mfma_f32_16x16x32_bf16(aL,bH,acc[g],0,0,0);
          }
        }
      }
    } else if (p <= 3){
      // gather pass p: units p*64 + j ; 12 waves, widx 0..11
      int widx = w - ((kq > p-1) ? 4 : 0);
      int u = p*64 + widx*4 + qi;
      int e = u >> 4, ri = u & 15;
      gather_unit(hin4, deg, adj, e, r0+ri, qi, ql,
                  &aHs[ri*ASTR + e*64 + ql*4], &aLs[ri*ASTR + e*64 + ql*4]);
      if (p < 3 && widx < 4){                  // second round (units 48..63 of this pass)
        int u2 = p*64 + 48 + widx*4 + qi;
        int e2 = u2 >> 4, ri2 = u2 & 15;
        gather_unit(hin4, deg, adj, e2, r0+ri2, qi, ql,
                    &aHs[ri2*ASTR + e2*64 + ql*4], &aLs[ri2*ASTR + e2*64 + ql*4]);
      }
    }
    __syncthreads();
  }

  // ---------- publish split-K partials: PS[(kq*12 + g*4+cb)][row][col] ----------
  {
    int crow0 = (lane>>4)*4;
    #pragma unroll
    for (int g=0;g<3;g++){
      float* slot = PSf + (size_t)(kq*12 + g*4 + cb)*PSTR;
      #pragma unroll
      for (int i=0;i<4;i++)
        slot[(crow0+i)*16 + l15] = acc[g][i];
    }
  }
  __syncthreads();

  // ---------- reduce + gates (all 1024 threads); ah back into PS slot (8+cb2) ----------
  {
    int r = tid >> 6, f = tid & 63;
    int cb2 = f >> 4, c = f & 15;
    float az=0.f, ar=0.f, ah=0.f;
    #pragma unroll
    for (int k=0;k<4;k++){
      az += PSf[(size_t)(k*12 + 0 + cb2)*PSTR + r*16 + c];
      ar += PSf[(size_t)(k*12 + 4 + cb2)*PSTR + r*16 + c];
      ah += PSf[(size_t)(k*12 + 8 + cb2)*PSTR + r*16 + c];
    }
    float z = 1.f/(1.f + expf(-(az + bz[f])));
    float rg = 1.f/(1.f + expf(-(ar + br[f])));
    float hv = hin[(size_t)(r0+r)*64 + f];
    zSf[tid] = z;
    rSf[tid] = rg;
    ushort hi,lo; split_bf(rg*hv,hi,lo);
    rhH[r*72+f] = hi;
    rhL[r*72+f] = lo;
    PSf[(size_t)(8 + cb2)*PSTR + r*16 + c] = ah;
  }
  __syncthreads();

  // ---------- waves 0..3: T = rh @ Ut, blend, write ----------
  if (w < 4){
    const int colf = w*16 + l15;
    float4v acc2 = {0.f,0.f,0.f,0.f};
    #pragma unroll
    for (int kk=0; kk<2; ++kk){
      short8 aH = *(const short8*)&rhH[l15*72 + kk*32 + koff];
      short8 aL = *(const short8*)&rhL[l15*72 + kk*32 + koff];
      int boff = (((w<<1) + kk) << 9) + lane*8;
      short8 bH = *(const short8*)(PUH + boff);
      short8 bL = *(const short8*)(PUL + boff);
      acc2 = __builtin_amdgcn_mfma_f32_16x16x32_bf16(aH,bH,acc2,0,0,0);
      acc2 = __builtin_amdgcn_mfma_f32_16x16x32_bf16(aH,bL,acc2,0,0,0);
      acc2 = __builtin_amdgcn_mfma_f32_16x16x32_bf16(aL,bH,acc2,0,0,0);
    }
    const int crow0 = (lane>>4)*4;
    const float bhf = bh[colf];
    #pragma unroll
    for (int i=0;i<4;i++){
      int row = crow0 + i;
      float ah = PSf[(size_t)(8 + w)*PSTR + row*16 + l15];
      float z  = zSf[row*64 + colf];
      float rg = rSf[row*64 + colf];
      float ht = tanhf(ah + acc2[i] + bhf);
      size_t idx = (size_t)(r0+row)*64 + colf;
      float hn = (1.f - z)*hin[idx] + rg*ht;
      hout[idx] = hn;
      if (last) out[idx] = hn;
    }
  }
}

extern "C" void kernel_launch(void* const* d_in, const int* in_sizes, int n_in,
                              void* d_out, int out_size, void* d_ws, size_t ws_size,
                              hipStream_t stream) {
  const float* x    = (const float*)d_in[0];
  const float* edge = (const float*)d_in[1];
  const float* wz   = (const float*)d_in[2];
  const float* wr   = (const float*)d_in[3];
  const float* wh   = (const float*)d_in[4];
  const float* uz   = (const float*)d_in[5];
  const float* ur   = (const float*)d_in[6];
  const float* uh   = (const float*)d_in[7];
  const float* bz   = (const float*)d_in[8];
  const float* br   = (const float*)d_in[9];
  const float* bh   = (const float*)d_in[10];
  float* out = (float*)d_out;

  char* ws = (char*)d_ws;
  size_t off = 0;
  auto alloc = [&](size_t bytes)->void*{
    void* p = ws + off;
    off = (off + bytes + 255) & ~(size_t)255;
    return p;
  };
  const size_t EN = (size_t)NE * N_NOTES;            // 57344
  const size_t ND = (size_t)N_NOTES * SIZE;          // 262144
  int*    deg  = (int*)   alloc(EN * 4);
  ushort* adj  = (ushort*)alloc(EN * MAXDEG * 2);
  ushort* PWH  = (ushort*)alloc((size_t)PWN * 2);
  ushort* PWL  = (ushort*)alloc((size_t)PWN * 2);
  ushort* PUH  = (ushort*)alloc((size_t)PUN * 2);
  ushort* PUL  = (ushort*)alloc((size_t)PUN * 2);
  float*  h0   = (float*) alloc((size_t)HPAD * SIZE * 4);
  float*  h1   = (float*) alloc((size_t)HPAD * SIZE * 4);

  k_zero <<<2048, 256, 0, stream>>>(deg, (uint32_t*)adj, h0 + ND, h1 + ND);
  k_build<<<NE*N_NOTES, 256, 0, stream>>>((const float4v*)edge, deg, adj);
  k_pack <<<(PWN + PUN)/256, 256, 0, stream>>>(wz, wr, wh, uz, ur, uh, PWH, PWL, PUH, PUL);
  hipMemcpyAsync(h0, x, ND*4, hipMemcpyDeviceToDevice, stream);

  float* hcur = h0;
  float* hnxt = h1;
  for (int it = 0; it < NITER; ++it){
    k_fused<<<N_NOTES/16, 1024, 0, stream>>>(deg, adj, PWH, PWL, PUH, PUL,
                                             bz, br, bh, hcur, hnxt,
                                             out, (it == NITER-1) ? 1 : 0);
    float* t = hcur; hcur = hnxt; hnxt = t;
  }
}